// Round 7
// baseline (237.227 us; speedup 1.0000x reference)
//
#include <hip/hip_runtime.h>
#include <hip/hip_bf16.h>
#include <math.h>

// Problem constants: B=8, C=512, T=2048, G=32, HEADS=8, CH=64
#define NB 8
#define NC 512
#define NT 2048
#define NG 32
#define NH 8
#define CH 64

typedef __attribute__((ext_vector_type(8))) short short8;   // 8 bf16
typedef __attribute__((ext_vector_type(4))) short short4v;  // 4 bf16 (8B)
typedef __attribute__((ext_vector_type(4))) float floatx4;  // MFMA C/D
typedef __attribute__((ext_vector_type(2))) unsigned int uintx2;
typedef __attribute__((ext_vector_type(4))) unsigned int uintx4;

static __device__ __forceinline__ short f2bf(float f) {
    __hip_bfloat16 h = __float2bfloat16(f);
    return *reinterpret_cast<short*>(&h);
}

// pack high halves of two f32 (truncation to bf16): 1 v_perm_b32
static __device__ __forceinline__ int pk2bf_trunc(float lo, float hi) {
    return (int)__builtin_amdgcn_perm(__builtin_bit_cast(unsigned, hi),
                                      __builtin_bit_cast(unsigned, lo),
                                      0x07060302u);
}

static __device__ __forceinline__ void gload_lds16(const short* g, short* l) {
    __builtin_amdgcn_global_load_lds(
        (const __attribute__((address_space(1))) void*)g,
        (__attribute__((address_space(3))) void*)l, 16, 0, 0);
}

// ---------------------------------------------------------------------------
// fp32 -> bf16 cast of both weight matrices in one launch
// ---------------------------------------------------------------------------
__global__ __launch_bounds__(256) void castw_kernel(
    const float* __restrict__ qw, const float* __restrict__ pw,
    short* __restrict__ qo, short* __restrict__ po)
{
    const int i = blockIdx.x * 256 + threadIdx.x;   // 0..262143 float4 groups
    const bool isq = i < 196608;                    // 1536*512/4
    const int j = isq ? i : i - 196608;
    float4 v = isq ? ((const float4*)qw)[j] : ((const float4*)pw)[j];
    short4v s;
    s.x = f2bf(v.x); s.y = f2bf(v.y); s.z = f2bf(v.z); s.w = f2bf(v.w);
    if (isq) *(short4v*)&qo[j * 4] = s;
    else     *(short4v*)&po[j * 4] = s;
}

// ---------------------------------------------------------------------------
// Fused GroupNorm (round-2 version, 256 threads). One block per (b,g);
// group staged once into LDS via global_load_lds, stats reduced,
// normalize+transpose+bf16 out.
// ---------------------------------------------------------------------------
__global__ __launch_bounds__(256) void gn_fused_kernel(
    const float* __restrict__ x, const float* __restrict__ gw,
    const float* __restrict__ gb, short* __restrict__ ht)
{
    __shared__ float xs[16 * NT];    // 128 KB
    __shared__ float red[16];
    const int tid = threadIdx.x;
    const int wv = tid >> 6, lane = tid & 63;
    const int f = blockIdx.x;        // 256 blocks
    const int b = f & 7, g = f >> 3; // XCD = b

    const float* src = x + ((size_t)b * NC + g * 16) * NT;

    // stage 8192 x 16B slots; wave-uniform LDS dest + per-lane global src
    #pragma unroll
    for (int i = 0; i < 32; ++i) {
        const int slot = i * 256 + tid;
        gload_lds16((const short*)src + (size_t)slot * 8,
                    (short*)&xs[(i * 256 + wv * 64) * 4]);
    }
    __syncthreads();   // drains vmcnt -> xs resident

    // stats
    float s = 0.f, ss = 0.f;
    #pragma unroll
    for (int i = 0; i < 32; ++i) {
        float4 v = ((const float4*)xs)[i * 256 + tid];
        s  += v.x + v.y + v.z + v.w;
        ss += v.x*v.x + v.y*v.y + v.z*v.z + v.w*v.w;
    }
    #pragma unroll
    for (int o = 32; o > 0; o >>= 1) {
        s  += __shfl_down(s,  o, 64);
        ss += __shfl_down(ss, o, 64);
    }
    if (lane == 0) { red[wv] = s; red[8 + wv] = ss; }
    __syncthreads();
    const float inv  = 1.f / 32768.f;
    const float mean = (red[0] + red[1] + red[2] + red[3]) * inv;
    const float var  = (red[8] + red[9] + red[10] + red[11]) * inv - mean * mean;
    const float rstd = rsqrtf(var + 1e-5f);

    float wc[16], bc[16];
    #pragma unroll
    for (int ch = 0; ch < 16; ++ch) {
        const float w = gw[g * 16 + ch] * rstd;
        wc[ch] = w;
        bc[ch] = gb[g * 16 + ch] - mean * w;
    }

    // apply: thread handles 2 quads of 4 consecutive t; LDS reads conflict-free
    #pragma unroll
    for (int k = 0; k < 2; ++k) {
        const int q = k * 256 + tid;          // t-quad 0..511
        float4 col[16];
        #pragma unroll
        for (int ch = 0; ch < 16; ++ch)
            col[ch] = *(const float4*)&xs[ch * NT + q * 4];
        short* dst = ht + ((size_t)b * NT + q * 4) * NC + g * 16;
        #pragma unroll
        for (int j = 0; j < 4; ++j) {
            short v16[16];
            #pragma unroll
            for (int ch = 0; ch < 16; ++ch) {
                const float xv = (j == 0) ? col[ch].x : (j == 1) ? col[ch].y
                               : (j == 2) ? col[ch].z : col[ch].w;
                v16[ch] = f2bf(xv * wc[ch] + bc[ch]);
            }
            *(short8*)&dst[(size_t)j * NC]     = *(const short8*)&v16[0];
            *(short8*)&dst[(size_t)j * NC + 8] = *(const short8*)&v16[8];
        }
    }
}

// ---------------------------------------------------------------------------
// QKV GEMM, R2 1-phase loop (known best; dbuf regressed per R6 + m99/m131).
// NEW: v-blocks (m0>=1024) write through a per-wave LDS transpose so vv gets
// 16B coalesced stores (was: 64 scalar 2B stores/lane at stride NT).
// q gets scale*log2e, k gets scale. XCD-aware remap kept.
// ---------------------------------------------------------------------------
#define BK 32
__global__ __launch_bounds__(256) void qkv_gemm_kernel(
    const short* __restrict__ wb, const short* __restrict__ ht,
    const float* __restrict__ bias,
    short* __restrict__ q_t, short* __restrict__ k_t, short* __restrict__ vv)
{
    __shared__ short smem[8192];          // As [0,4096) | Bs [4096,8192)
    short* As = smem;
    short* Bs = smem + 4096;
    const int tid = threadIdx.x;
    const int wv = tid >> 6, lane = tid & 63;
    const int l16 = lane & 15, quad = lane >> 4;
    // bijective XCD swizzle: 1536 blocks = 8 XCD x (16 n-cols x 12 m-rows)
    const int fblk = blockIdx.y * 128 + blockIdx.x;   // x-fastest flat id
    const int jx = fblk >> 3, xcd = fblk & 7;
    const int n0 = (xcd * 16 + jx / 12) * 128;
    const int m0 = (jx % 12) * 128;
    const int wm = wv & 1, wn = wv >> 1;

    floatx4 acc[4][4];
    #pragma unroll
    for (int i = 0; i < 4; ++i)
        #pragma unroll
        for (int j = 0; j < 4; ++j) acc[i][j] = (floatx4){0.f, 0.f, 0.f, 0.f};

    const short* gsrc = (wv < 2) ? wb : ht;
    const int rbase = (wv & 1) * 64;
    const int tile0 = (wv < 2) ? m0 : n0;
    short* lbuf = (wv < 2) ? As : Bs;
    const int lrow = lane >> 2;
    const int lcol = (lane & 3) * 8;

    for (int k0 = 0; k0 < 512; k0 += BK) {
        __syncthreads();
        #pragma unroll
        for (int ch = 0; ch < 4; ++ch) {
            const int row = rbase + ch * 16 + lrow;
            gload_lds16(gsrc + (size_t)(tile0 + row) * 512 + k0 + lcol,
                        lbuf + (rbase + ch * 16) * BK);
        }
        __syncthreads();

        short8 af[4], bfr[4];
        #pragma unroll
        for (int i = 0; i < 4; ++i) {
            af[i]  = *(const short8*)&As[(wm * 64 + i * 16 + l16) * BK + quad * 8];
            bfr[i] = *(const short8*)&Bs[(wn * 64 + i * 16 + l16) * BK + quad * 8];
        }
        #pragma unroll
        for (int i = 0; i < 4; ++i)
            #pragma unroll
            for (int j = 0; j < 4; ++j)
                acc[i][j] = __builtin_amdgcn_mfma_f32_16x16x32_bf16(
                    af[i], bfr[j], acc[i][j], 0, 0, 0);
    }

    if (m0 < 1024) {
        // ---- q/k epilogue (unchanged): coalesced 8B stores ----
        const float kscale = 0.35355339059327373f;              // 64^-0.25
        const float qscale = 0.35355339059327373f * 1.4426950408889634f; // *log2e
        #pragma unroll
        for (int i = 0; i < 4; ++i) {
            const int o16 = m0 + wm * 64 + i * 16;
            const int sel = o16 >> 9;
            const int hh  = (o16 >> 6) & 7;
            const int c16 = o16 & 63;
            const float4 b4 = *(const float4*)&bias[o16 + quad * 4];
            const float sc = (sel == 0) ? qscale : kscale;
            #pragma unroll
            for (int j = 0; j < 4; ++j) {
                const int tg = n0 + wn * 64 + j * 16 + l16;
                const int b = tg >> 11, t = tg & 2047;
                floatx4 v = acc[i][j];
                short4v s;
                s.x = f2bf((v[0] + b4.x) * sc); s.y = f2bf((v[1] + b4.y) * sc);
                s.z = f2bf((v[2] + b4.z) * sc); s.w = f2bf((v[3] + b4.w) * sc);
                short* dst = (sel == 0 ? q_t : k_t) +
                    (((size_t)(b * NH + hh) * NT + t) * CH + c16 + quad * 4);
                *(short4v*)dst = s;
            }
        }
    } else {
        // ---- v epilogue: per-wave LDS transpose -> coalesced 16B stores ----
        __syncthreads();                 // all frag reads done; reuse smem
        short* scr = smem + wv * 2048;   // 32 rows x 64 shorts (4 KB) per wave
        const int b    = (n0 + wn * 64) >> 11;
        const int t_lo = (n0 + wn * 64) & 2047;
        #pragma unroll
        for (int h = 0; h < 2; ++h) {
            // write phase: 32x64 chunk (o-local = i2*16+quad*4+r, t = j*16+l16)
            #pragma unroll
            for (int i2 = 0; i2 < 2; ++i2) {
                const int i = h * 2 + i2;
                const int o16 = m0 + wm * 64 + i * 16;
                const float4 b4 = *(const float4*)&bias[o16 + quad * 4];
                #pragma unroll
                for (int j = 0; j < 4; ++j) {
                    floatx4 v = acc[i][j];
                    const int rb = (i2 * 16 + quad * 4) * 64 + j * 16 + l16;
                    scr[rb]       = f2bf(v[0] + b4.x);
                    scr[rb + 64]  = f2bf(v[1] + b4.y);
                    scr[rb + 128] = f2bf(v[2] + b4.z);
                    scr[rb + 192] = f2bf(v[3] + b4.w);
                }
            }
            asm volatile("s_waitcnt lgkmcnt(0)" ::: "memory");
            __builtin_amdgcn_sched_barrier(0);
            // read+store phase: rows of 128B -> 16B coalesced global stores
            #pragma unroll
            for (int s = 0; s < 4; ++s) {
                const int slot = s * 64 + lane;
                const int row = slot >> 3, cg = slot & 7;
                const int ov = m0 - 1024 + wm * 64 + h * 32 + row;  // 0..511
                const int hh = ov >> 6, c = ov & 63;
                short8 val = *(const short8*)&scr[row * 64 + cg * 8];
                *(short8*)&vv[((size_t)(b * NH + hh) * CH + c) * NT +
                              t_lo + cg * 8] = val;
            }
            asm volatile("s_waitcnt lgkmcnt(0)" ::: "memory");
            __builtin_amdgcn_sched_barrier(0);
        }
    }
}

// ---------------------------------------------------------------------------
// Flash attention v9 (best measured: 80.0 us). In-register P via permlane
// (T12) + XCD-locality block remap (T1). 8 waves x 32 rows, 512 thr,
// 2 blocks/CU. Unchanged from round 6.
// ---------------------------------------------------------------------------
__global__ __launch_bounds__(512, 4) void attn_kernel(
    const short* __restrict__ qg, const short* __restrict__ kg,
    const short* __restrict__ vg, short* __restrict__ at)
{
    __shared__ short kt[2][64 * 64];     // 16 KB: [ss][c] swizzled, dbuf
    __shared__ short vs[2][64 * 64];     // 16 KB: [c][ss] swizzled, dbuf

    const int tid = threadIdx.x;          // 0..511
    const int wv = tid >> 6, lane = tid & 63;
    const int l16 = lane & 15, quad = lane >> 4;
    const int xr = l16 & 7;
    // XCD-locality remap: f%8 pinned per bh
    const int f = blockIdx.y * 8 + blockIdx.x;    // x-fastest flat id
    const int t0 = (f >> 6) * 256;
    const int bh = ((f >> 3) & 7) * 8 + (f & 7);
    const int b = bh >> 3, hd = bh & 7;
    const short* qh = qg + (size_t)bh * NT * CH;
    const short* kh = kg + (size_t)bh * NT * CH;
    const short* vh = vg + (size_t)bh * CH * NT;

    // K/V tile 0 into buf 0: 512 lane-slots each = 1 gload per thread
    {
        const int row = tid >> 3, cc = (tid & 7) ^ (row & 7);
        gload_lds16(kh + (size_t)row * CH + cc * 8, &kt[0][wv * 512]);
        gload_lds16(vh + (size_t)row * NT + cc * 8, &vs[0][wv * 512]);
    }

    // Q frags direct global->reg. B-frag: col = tt row, k = ks*32+quad*8+j.
    short8 bq[2][2];
    #pragma unroll
    for (int qt = 0; qt < 2; ++qt) {
        const int row = t0 + wv * 32 + qt * 16 + l16;
        #pragma unroll
        for (int ks = 0; ks < 2; ++ks)
            bq[qt][ks] = *(const short8*)&qh[(size_t)row * CH + ks * 32 + quad * 8];
    }
    __syncthreads();   // tile0 resident

    floatx4 Oa[4][2];   // [ct][qt]: D[c][tt]
    #pragma unroll
    for (int ct = 0; ct < 4; ++ct)
        #pragma unroll
        for (int qt = 0; qt < 2; ++qt) Oa[ct][qt] = (floatx4){0.f, 0.f, 0.f, 0.f};
    float l_part[2] = {0.f, 0.f};   // per-lane partial sums

    for (int it = 0; it < NT / 64; ++it) {
        __syncthreads();   // cur tile ready; prev tile frag reads done
        if (it + 1 < NT / 64) {
            const int s0n = (it + 1) * 64;
            const int row = tid >> 3, cc = (tid & 7) ^ (row & 7);
            gload_lds16(kh + (size_t)(s0n + row) * CH + cc * 8,
                        &kt[(it + 1) & 1][wv * 512]);
            gload_lds16(vh + (size_t)row * NT + s0n + cc * 8,
                        &vs[(it + 1) & 1][wv * 512]);
        }
        const short* kc = kt[it & 1];
        const short* vc = vs[it & 1];

        // ---- S: D[ss][tt]; each K frag feeds 2 tt-tiles ----
        floatx4 sacc[4][2];   // [nt=ss-tile][qt=tt-tile]
        #pragma unroll
        for (int nt = 0; nt < 4; ++nt)
            #pragma unroll
            for (int qt = 0; qt < 2; ++qt) sacc[nt][qt] = (floatx4){0.f, 0.f, 0.f, 0.f};
        __builtin_amdgcn_s_setprio(1);
        #pragma unroll
        for (int ks = 0; ks < 2; ++ks) {
            const int c = (quad | (ks << 2)) ^ xr;
            #pragma unroll
            for (int nt = 0; nt < 4; ++nt) {
                short8 ak = *(const short8*)&kc[(nt * 16 + l16) * 64 + c * 8];
                #pragma unroll
                for (int qt = 0; qt < 2; ++qt)
                    sacc[nt][qt] = __builtin_amdgcn_mfma_f32_16x16x32_bf16(
                        ak, bq[qt][ks], sacc[nt][qt], 0, 0, 0);
            }
        }
        __builtin_amdgcn_s_setprio(0);

        // ---- softmax: exp2 (no max), sums + bf16 trunc-pack in-register ----
        unsigned pk01[2][4], pk23[2][4];
        #pragma unroll
        for (int qt = 0; qt < 2; ++qt) {
            float sn[4];
            #pragma unroll
            for (int nt = 0; nt < 4; ++nt) {
                const float p0 = __builtin_amdgcn_exp2f(sacc[nt][qt][0]);
                const float p1 = __builtin_amdgcn_exp2f(sacc[nt][qt][1]);
                const float p2 = __builtin_amdgcn_exp2f(sacc[nt][qt][2]);
                const float p3 = __builtin_amdgcn_exp2f(sacc[nt][qt][3]);
                sn[nt] = (p0 + p1) + (p2 + p3);
                pk01[qt][nt] = (unsigned)pk2bf_trunc(p0, p1);
                pk23[qt][nt] = (unsigned)pk2bf_trunc(p2, p3);
            }
            l_part[qt] += (sn[0] + sn[1]) + (sn[2] + sn[3]);
        }

        // ---- PV: B-frag via permlane swaps ----
        #pragma unroll
        for (int ks = 0; ks < 2; ++ks) {
            short8 bp[2];
            #pragma unroll
            for (int qt = 0; qt < 2; ++qt) {
                uintx2 a = __builtin_amdgcn_permlane32_swap(
                    pk01[qt][2 * ks], pk01[qt][2 * ks + 1], false, false);
                uintx2 w02 = __builtin_amdgcn_permlane16_swap(a.x, a.y, false, false);
                uintx2 c2 = __builtin_amdgcn_permlane32_swap(
                    pk23[qt][2 * ks], pk23[qt][2 * ks + 1], false, false);
                uintx2 w13 = __builtin_amdgcn_permlane16_swap(c2.x, c2.y, false, false);
                uintx4 wi = (uintx4){w02.x, w13.x, w02.y, w13.y};
                bp[qt] = __builtin_bit_cast(short8, wi);
            }
            const int c = (quad | (ks << 2)) ^ xr;
            __builtin_amdgcn_s_setprio(1);
            #pragma unroll
            for (int ct = 0; ct < 4; ++ct) {
                short8 av = *(const short8*)&vc[(ct * 16 + l16) * 64 + c * 8];
                #pragma unroll
                for (int qt = 0; qt < 2; ++qt)
                    Oa[ct][qt] = __builtin_amdgcn_mfma_f32_16x16x32_bf16(
                        av, bp[qt], Oa[ct][qt], 0, 0, 0);
            }
            __builtin_amdgcn_s_setprio(0);
        }
    }

    // epilogue: reduce l across quads, normalize, write attn_t[b][t][hd*64+c]
    #pragma unroll
    for (int qt = 0; qt < 2; ++qt) {
        float l = l_part[qt];
        l += __shfl_xor(l, 16, 64);
        l += __shfl_xor(l, 32, 64);
        const float rl = 1.f / l;
        const int t = t0 + wv * 32 + qt * 16 + l16;
        short* dst = at + ((size_t)b * NT + t) * NC + hd * CH;
        #pragma unroll
        for (int ct = 0; ct < 4; ++ct) {
            int2 s;
            s.x = pk2bf_trunc(Oa[ct][qt][0] * rl, Oa[ct][qt][1] * rl);
            s.y = pk2bf_trunc(Oa[ct][qt][2] * rl, Oa[ct][qt][3] * rl);
            *(int2*)&dst[ct * 16 + quad * 4] = s;
        }
    }
}

// ---------------------------------------------------------------------------
// Proj GEMM + bias + residual, R2 1-phase loop restored. XCD remap kept.
// ---------------------------------------------------------------------------
__global__ __launch_bounds__(256) void proj_gemm_kernel(
    const short* __restrict__ wb, const short* __restrict__ at,
    const float* __restrict__ bias, const float* __restrict__ xres,
    float* __restrict__ out)
{
    __shared__ short As[128 * BK];
    __shared__ short Bs[128 * BK];
    const int tid = threadIdx.x;
    const int wv = tid >> 6, lane = tid & 63;
    const int l16 = lane & 15, quad = lane >> 4;
    const int fblk = blockIdx.y * 128 + blockIdx.x;   // x-fastest flat id
    const int jx = fblk >> 3, xcd = fblk & 7;
    const int n0 = (xcd * 16 + (jx >> 2)) * 128;
    const int m0 = (jx & 3) * 128;
    const int wm = wv & 1, wn = wv >> 1;

    floatx4 acc[4][4];
    #pragma unroll
    for (int i = 0; i < 4; ++i)
        #pragma unroll
        for (int j = 0; j < 4; ++j) acc[i][j] = (floatx4){0.f, 0.f, 0.f, 0.f};

    const short* gsrc = (wv < 2) ? wb : at;
    const int rbase = (wv & 1) * 64;
    const int tile0 = (wv < 2) ? m0 : n0;
    short* lbuf = (wv < 2) ? As : Bs;
    const int lrow = lane >> 2;
    const int lcol = (lane & 3) * 8;

    for (int k0 = 0; k0 < 512; k0 += BK) {
        __syncthreads();
        #pragma unroll
        for (int ch = 0; ch < 4; ++ch) {
            const int row = rbase + ch * 16 + lrow;
            gload_lds16(gsrc + (size_t)(tile0 + row) * 512 + k0 + lcol,
                        lbuf + (rbase + ch * 16) * BK);
        }
        __syncthreads();

        short8 af[4], bfr[4];
        #pragma unroll
        for (int i = 0; i < 4; ++i) {
            af[i]  = *(const short8*)&As[(wm * 64 + i * 16 + l16) * BK + quad * 8];
            bfr[i] = *(const short8*)&Bs[(wn * 64 + i * 16 + l16) * BK + quad * 8];
        }
        #pragma unroll
        for (int i = 0; i < 4; ++i)
            #pragma unroll
            for (int j = 0; j < 4; ++j)
                acc[i][j] = __builtin_amdgcn_mfma_f32_16x16x32_bf16(
                    af[i], bfr[j], acc[i][j], 0, 0, 0);
    }

    #pragma unroll
    for (int i = 0; i < 4; ++i) {
        const int o16 = m0 + wm * 64 + i * 16;
        const float4 b4 = *(const float4*)&bias[o16 + quad * 4];
        #pragma unroll
        for (int j = 0; j < 4; ++j) {
            const int tg = n0 + wn * 64 + j * 16 + l16;
            const int b = tg >> 11, t = tg & 2047;
            const size_t base = ((size_t)b * NC + o16 + quad * 4) * NT + t;
            floatx4 v = acc[i][j];
            out[base]          = v[0] + b4.x + xres[base];
            out[base + NT]     = v[1] + b4.y + xres[base + NT];
            out[base + 2 * NT] = v[2] + b4.z + xres[base + 2 * NT];
            out[base + 3 * NT] = v[3] + b4.w + xres[base + 3 * NT];
        }
    }
}

// ---------------------------------------------------------------------------
extern "C" void kernel_launch(void* const* d_in, const int* in_sizes, int n_in,
                              void* d_out, int out_size, void* d_ws, size_t ws_size,
                              hipStream_t stream)
{
    const float* x      = (const float*)d_in[0];
    const float* gn_w   = (const float*)d_in[1];
    const float* gn_b   = (const float*)d_in[2];
    const float* qkv_w  = (const float*)d_in[3];
    const float* qkv_b  = (const float*)d_in[4];
    const float* proj_w = (const float*)d_in[5];
    const float* proj_b = (const float*)d_in[6];
    float* out = (float*)d_out;

    short* ht  = (short*)d_ws;            // [8*2048][512]
    short* q_t = ht  + 8388608;           // [64][2048][64]
    short* k_t = q_t + 8388608;
    short* vv  = k_t + 8388608;           // [64][64][2048]
    short* at  = vv  + 8388608;           // [8*2048][512]
    short* qwb = at  + 8388608;           // [1536][512]
    short* pwb = qwb + 786432;            // [512][512]

    castw_kernel<<<1024, 256, 0, stream>>>(qkv_w, proj_w, qwb, pwb);
    gn_fused_kernel<<<NB * NG, 256, 0, stream>>>(x, gn_w, gn_b, ht);
    qkv_gemm_kernel<<<dim3(128, 12), 256, 0, stream>>>(qwb, ht, qkv_b, q_t, k_t, vv);
    attn_kernel<<<dim3(8, 64), 512, 0, stream>>>(q_t, k_t, vv, at);
    proj_gemm_kernel<<<dim3(128, 4), 256, 0, stream>>>(pwb, at, proj_b, x, out);
}

// Round 8
// 223.846 us; speedup vs baseline: 1.0598x; 1.0598x over previous
//
#include <hip/hip_runtime.h>
#include <hip/hip_bf16.h>
#include <math.h>

// Problem constants: B=8, C=512, T=2048, G=32, HEADS=8, CH=64
#define NB 8
#define NC 512
#define NT 2048
#define NG 32
#define NH 8
#define CH 64

typedef __attribute__((ext_vector_type(8))) short short8;   // 8 bf16
typedef __attribute__((ext_vector_type(4))) short short4v;  // 4 bf16 (8B)
typedef __attribute__((ext_vector_type(4))) float floatx4;  // MFMA C/D
typedef __attribute__((ext_vector_type(2))) unsigned int uintx2;
typedef __attribute__((ext_vector_type(4))) unsigned int uintx4;

static __device__ __forceinline__ short f2bf(float f) {
    __hip_bfloat16 h = __float2bfloat16(f);
    return *reinterpret_cast<short*>(&h);
}

// pack high halves of two f32 (truncation to bf16): 1 v_perm_b32
static __device__ __forceinline__ int pk2bf_trunc(float lo, float hi) {
    return (int)__builtin_amdgcn_perm(__builtin_bit_cast(unsigned, hi),
                                      __builtin_bit_cast(unsigned, lo),
                                      0x07060302u);
}

static __device__ __forceinline__ void gload_lds16(const short* g, short* l) {
    __builtin_amdgcn_global_load_lds(
        (const __attribute__((address_space(1))) void*)g,
        (__attribute__((address_space(3))) void*)l, 16, 0, 0);
}

// ---------------------------------------------------------------------------
// fp32 -> bf16 cast of both weight matrices in one launch
// ---------------------------------------------------------------------------
__global__ __launch_bounds__(256) void castw_kernel(
    const float* __restrict__ qw, const float* __restrict__ pw,
    short* __restrict__ qo, short* __restrict__ po)
{
    const int i = blockIdx.x * 256 + threadIdx.x;   // 0..262143 float4 groups
    const bool isq = i < 196608;                    // 1536*512/4
    const int j = isq ? i : i - 196608;
    float4 v = isq ? ((const float4*)qw)[j] : ((const float4*)pw)[j];
    short4v s;
    s.x = f2bf(v.x); s.y = f2bf(v.y); s.z = f2bf(v.z); s.w = f2bf(v.w);
    if (isq) *(short4v*)&qo[j * 4] = s;
    else     *(short4v*)&po[j * 4] = s;
}

// ---------------------------------------------------------------------------
// Fused GroupNorm (round-2 version, 256 threads). One block per (b,g);
// group staged once into LDS via global_load_lds, stats reduced,
// normalize+transpose+bf16 out.
// ---------------------------------------------------------------------------
__global__ __launch_bounds__(256) void gn_fused_kernel(
    const float* __restrict__ x, const float* __restrict__ gw,
    const float* __restrict__ gb, short* __restrict__ ht)
{
    __shared__ float xs[16 * NT];    // 128 KB
    __shared__ float red[16];
    const int tid = threadIdx.x;
    const int wv = tid >> 6, lane = tid & 63;
    const int f = blockIdx.x;        // 256 blocks
    const int b = f & 7, g = f >> 3; // XCD = b

    const float* src = x + ((size_t)b * NC + g * 16) * NT;

    // stage 8192 x 16B slots; wave-uniform LDS dest + per-lane global src
    #pragma unroll
    for (int i = 0; i < 32; ++i) {
        const int slot = i * 256 + tid;
        gload_lds16((const short*)src + (size_t)slot * 8,
                    (short*)&xs[(i * 256 + wv * 64) * 4]);
    }
    __syncthreads();   // drains vmcnt -> xs resident

    // stats
    float s = 0.f, ss = 0.f;
    #pragma unroll
    for (int i = 0; i < 32; ++i) {
        float4 v = ((const float4*)xs)[i * 256 + tid];
        s  += v.x + v.y + v.z + v.w;
        ss += v.x*v.x + v.y*v.y + v.z*v.z + v.w*v.w;
    }
    #pragma unroll
    for (int o = 32; o > 0; o >>= 1) {
        s  += __shfl_down(s,  o, 64);
        ss += __shfl_down(ss, o, 64);
    }
    if (lane == 0) { red[wv] = s; red[8 + wv] = ss; }
    __syncthreads();
    const float inv  = 1.f / 32768.f;
    const float mean = (red[0] + red[1] + red[2] + red[3]) * inv;
    const float var  = (red[8] + red[9] + red[10] + red[11]) * inv - mean * mean;
    const float rstd = rsqrtf(var + 1e-5f);

    float wc[16], bc[16];
    #pragma unroll
    for (int ch = 0; ch < 16; ++ch) {
        const float w = gw[g * 16 + ch] * rstd;
        wc[ch] = w;
        bc[ch] = gb[g * 16 + ch] - mean * w;
    }

    // apply: thread handles 2 quads of 4 consecutive t; LDS reads conflict-free
    #pragma unroll
    for (int k = 0; k < 2; ++k) {
        const int q = k * 256 + tid;          // t-quad 0..511
        float4 col[16];
        #pragma unroll
        for (int ch = 0; ch < 16; ++ch)
            col[ch] = *(const float4*)&xs[ch * NT + q * 4];
        short* dst = ht + ((size_t)b * NT + q * 4) * NC + g * 16;
        #pragma unroll
        for (int j = 0; j < 4; ++j) {
            short v16[16];
            #pragma unroll
            for (int ch = 0; ch < 16; ++ch) {
                const float xv = (j == 0) ? col[ch].x : (j == 1) ? col[ch].y
                               : (j == 2) ? col[ch].z : col[ch].w;
                v16[ch] = f2bf(xv * wc[ch] + bc[ch]);
            }
            *(short8*)&dst[(size_t)j * NC]     = *(const short8*)&v16[0];
            *(short8*)&dst[(size_t)j * NC + 8] = *(const short8*)&v16[8];
        }
    }
}

// ---------------------------------------------------------------------------
// QKV GEMM: BK=64 (8 iters, 16 barriers -- was 32) + XOR-swizzled LDS
// (attn-proven chunk^(row&7) pattern; pre-swizzled global src + linear
// gload_lds dest, T2/rule-21) -> conflict-free ds_read_b128 frag reads.
// ks=0,1 inner order reproduces two BK=32 iterations: bit-identical.
// R2 epilogue restored verbatim. XCD-aware remap kept.
// ---------------------------------------------------------------------------
#define BK 64
__global__ __launch_bounds__(256) void qkv_gemm_kernel(
    const short* __restrict__ wb, const short* __restrict__ ht,
    const float* __restrict__ bias,
    short* __restrict__ q_t, short* __restrict__ k_t, short* __restrict__ vv)
{
    __shared__ short As[128 * BK];   // 16 KB
    __shared__ short Bs[128 * BK];   // 16 KB
    const int tid = threadIdx.x;
    const int wv = tid >> 6, lane = tid & 63;
    const int l16 = lane & 15, quad = lane >> 4;
    const int xr = l16 & 7;
    // bijective XCD swizzle: 1536 blocks = 8 XCD x (16 n-cols x 12 m-rows)
    const int fblk = blockIdx.y * 128 + blockIdx.x;   // x-fastest flat id
    const int jx = fblk >> 3, xcd = fblk & 7;
    const int n0 = (xcd * 16 + jx / 12) * 128;
    const int m0 = (jx % 12) * 128;
    const int wm = wv & 1, wn = wv >> 1;

    floatx4 acc[4][4];
    #pragma unroll
    for (int i = 0; i < 4; ++i)
        #pragma unroll
        for (int j = 0; j < 4; ++j) acc[i][j] = (floatx4){0.f, 0.f, 0.f, 0.f};

    const short* gsrc = (wv < 2) ? wb : ht;
    const int rbase = (wv & 1) * 64;
    const int tile0 = (wv < 2) ? m0 : n0;
    short* lbuf = (wv < 2) ? As : Bs;
    const int srow = lane >> 3;      // 0..7
    const int schk = lane & 7;       // 0..7

    for (int k0 = 0; k0 < 512; k0 += BK) {
        __syncthreads();
        #pragma unroll
        for (int ch = 0; ch < 8; ++ch) {
            const int row = rbase + ch * 8 + srow;
            const int cc = schk ^ (row & 7);
            gload_lds16(gsrc + (size_t)(tile0 + row) * 512 + k0 + cc * 8,
                        lbuf + (rbase + ch * 8) * BK);
        }
        __syncthreads();

        #pragma unroll
        for (int ks = 0; ks < 2; ++ks) {
            const int c = (quad | (ks << 2)) ^ xr;
            short8 af[4], bfr[4];
            #pragma unroll
            for (int i = 0; i < 4; ++i) {
                af[i]  = *(const short8*)&As[(wm * 64 + i * 16 + l16) * BK + c * 8];
                bfr[i] = *(const short8*)&Bs[(wn * 64 + i * 16 + l16) * BK + c * 8];
            }
            #pragma unroll
            for (int i = 0; i < 4; ++i)
                #pragma unroll
                for (int j = 0; j < 4; ++j)
                    acc[i][j] = __builtin_amdgcn_mfma_f32_16x16x32_bf16(
                        af[i], bfr[j], acc[i][j], 0, 0, 0);
        }
    }

    const float kscale = 0.35355339059327373f;              // 64^-0.25
    const float qscale = 0.35355339059327373f * 1.4426950408889634f; // * log2(e)
    #pragma unroll
    for (int i = 0; i < 4; ++i) {
        const int o16 = m0 + wm * 64 + i * 16;
        const int sel = o16 >> 9;
        const int hh  = (o16 >> 6) & 7;
        const int c16 = o16 & 63;
        const float4 b4 = *(const float4*)&bias[o16 + quad * 4];
        const float sc = (sel == 0) ? qscale : kscale;
        #pragma unroll
        for (int j = 0; j < 4; ++j) {
            const int tg = n0 + wn * 64 + j * 16 + l16;
            const int b = tg >> 11, t = tg & 2047;
            floatx4 v = acc[i][j];
            v[0] += b4.x; v[1] += b4.y; v[2] += b4.z; v[3] += b4.w;
            if (sel < 2) {
                short4v s;
                s.x = f2bf(v[0] * sc); s.y = f2bf(v[1] * sc);
                s.z = f2bf(v[2] * sc); s.w = f2bf(v[3] * sc);
                short* dst = (sel == 0 ? q_t : k_t) +
                    (((size_t)(b * NH + hh) * NT + t) * CH + c16 + quad * 4);
                *(short4v*)dst = s;
            } else {
                short* dst = vv + ((size_t)(b * NH + hh) * CH + c16 + quad * 4) * NT + t;
                #pragma unroll
                for (int r = 0; r < 4; ++r) dst[(size_t)r * NT] = f2bf(v[r]);
            }
        }
    }
}

// ---------------------------------------------------------------------------
// Flash attention v9 (best measured: 80.0 us). In-register P via permlane
// (T12) + XCD-locality block remap (T1). 8 waves x 32 rows, 512 thr,
// 2 blocks/CU. Unchanged.
// ---------------------------------------------------------------------------
__global__ __launch_bounds__(512, 4) void attn_kernel(
    const short* __restrict__ qg, const short* __restrict__ kg,
    const short* __restrict__ vg, short* __restrict__ at)
{
    __shared__ short kt[2][64 * 64];     // 16 KB: [ss][c] swizzled, dbuf
    __shared__ short vs[2][64 * 64];     // 16 KB: [c][ss] swizzled, dbuf

    const int tid = threadIdx.x;          // 0..511
    const int wv = tid >> 6, lane = tid & 63;
    const int l16 = lane & 15, quad = lane >> 4;
    const int xr = l16 & 7;
    // XCD-locality remap: f%8 pinned per bh
    const int f = blockIdx.y * 8 + blockIdx.x;    // x-fastest flat id
    const int t0 = (f >> 6) * 256;
    const int bh = ((f >> 3) & 7) * 8 + (f & 7);
    const int b = bh >> 3, hd = bh & 7;
    const short* qh = qg + (size_t)bh * NT * CH;
    const short* kh = kg + (size_t)bh * NT * CH;
    const short* vh = vg + (size_t)bh * CH * NT;

    // K/V tile 0 into buf 0: 512 lane-slots each = 1 gload per thread
    {
        const int row = tid >> 3, cc = (tid & 7) ^ (row & 7);
        gload_lds16(kh + (size_t)row * CH + cc * 8, &kt[0][wv * 512]);
        gload_lds16(vh + (size_t)row * NT + cc * 8, &vs[0][wv * 512]);
    }

    // Q frags direct global->reg. B-frag: col = tt row, k = ks*32+quad*8+j.
    short8 bq[2][2];
    #pragma unroll
    for (int qt = 0; qt < 2; ++qt) {
        const int row = t0 + wv * 32 + qt * 16 + l16;
        #pragma unroll
        for (int ks = 0; ks < 2; ++ks)
            bq[qt][ks] = *(const short8*)&qh[(size_t)row * CH + ks * 32 + quad * 8];
    }
    __syncthreads();   // tile0 resident

    floatx4 Oa[4][2];   // [ct][qt]: D[c][tt]
    #pragma unroll
    for (int ct = 0; ct < 4; ++ct)
        #pragma unroll
        for (int qt = 0; qt < 2; ++qt) Oa[ct][qt] = (floatx4){0.f, 0.f, 0.f, 0.f};
    float l_part[2] = {0.f, 0.f};   // per-lane partial sums

    for (int it = 0; it < NT / 64; ++it) {
        __syncthreads();   // cur tile ready; prev tile frag reads done
        if (it + 1 < NT / 64) {
            const int s0n = (it + 1) * 64;
            const int row = tid >> 3, cc = (tid & 7) ^ (row & 7);
            gload_lds16(kh + (size_t)(s0n + row) * CH + cc * 8,
                        &kt[(it + 1) & 1][wv * 512]);
            gload_lds16(vh + (size_t)row * NT + s0n + cc * 8,
                        &vs[(it + 1) & 1][wv * 512]);
        }
        const short* kc = kt[it & 1];
        const short* vc = vs[it & 1];

        // ---- S: D[ss][tt]; each K frag feeds 2 tt-tiles ----
        floatx4 sacc[4][2];   // [nt=ss-tile][qt=tt-tile]
        #pragma unroll
        for (int nt = 0; nt < 4; ++nt)
            #pragma unroll
            for (int qt = 0; qt < 2; ++qt) sacc[nt][qt] = (floatx4){0.f, 0.f, 0.f, 0.f};
        __builtin_amdgcn_s_setprio(1);
        #pragma unroll
        for (int ks = 0; ks < 2; ++ks) {
            const int c = (quad | (ks << 2)) ^ xr;
            #pragma unroll
            for (int nt = 0; nt < 4; ++nt) {
                short8 ak = *(const short8*)&kc[(nt * 16 + l16) * 64 + c * 8];
                #pragma unroll
                for (int qt = 0; qt < 2; ++qt)
                    sacc[nt][qt] = __builtin_amdgcn_mfma_f32_16x16x32_bf16(
                        ak, bq[qt][ks], sacc[nt][qt], 0, 0, 0);
            }
        }
        __builtin_amdgcn_s_setprio(0);

        // ---- softmax: exp2 (no max), sums + bf16 trunc-pack in-register ----
        unsigned pk01[2][4], pk23[2][4];
        #pragma unroll
        for (int qt = 0; qt < 2; ++qt) {
            float sn[4];
            #pragma unroll
            for (int nt = 0; nt < 4; ++nt) {
                const float p0 = __builtin_amdgcn_exp2f(sacc[nt][qt][0]);
                const float p1 = __builtin_amdgcn_exp2f(sacc[nt][qt][1]);
                const float p2 = __builtin_amdgcn_exp2f(sacc[nt][qt][2]);
                const float p3 = __builtin_amdgcn_exp2f(sacc[nt][qt][3]);
                sn[nt] = (p0 + p1) + (p2 + p3);
                pk01[qt][nt] = (unsigned)pk2bf_trunc(p0, p1);
                pk23[qt][nt] = (unsigned)pk2bf_trunc(p2, p3);
            }
            l_part[qt] += (sn[0] + sn[1]) + (sn[2] + sn[3]);
        }

        // ---- PV: B-frag via permlane swaps ----
        #pragma unroll
        for (int ks = 0; ks < 2; ++ks) {
            short8 bp[2];
            #pragma unroll
            for (int qt = 0; qt < 2; ++qt) {
                uintx2 a = __builtin_amdgcn_permlane32_swap(
                    pk01[qt][2 * ks], pk01[qt][2 * ks + 1], false, false);
                uintx2 w02 = __builtin_amdgcn_permlane16_swap(a.x, a.y, false, false);
                uintx2 c2 = __builtin_amdgcn_permlane32_swap(
                    pk23[qt][2 * ks], pk23[qt][2 * ks + 1], false, false);
                uintx2 w13 = __builtin_amdgcn_permlane16_swap(c2.x, c2.y, false, false);
                uintx4 wi = (uintx4){w02.x, w13.x, w02.y, w13.y};
                bp[qt] = __builtin_bit_cast(short8, wi);
            }
            const int c = (quad | (ks << 2)) ^ xr;
            __builtin_amdgcn_s_setprio(1);
            #pragma unroll
            for (int ct = 0; ct < 4; ++ct) {
                short8 av = *(const short8*)&vc[(ct * 16 + l16) * 64 + c * 8];
                #pragma unroll
                for (int qt = 0; qt < 2; ++qt)
                    Oa[ct][qt] = __builtin_amdgcn_mfma_f32_16x16x32_bf16(
                        av, bp[qt], Oa[ct][qt], 0, 0, 0);
            }
            __builtin_amdgcn_s_setprio(0);
        }
    }

    // epilogue: reduce l across quads, normalize, write attn_t[b][t][hd*64+c]
    #pragma unroll
    for (int qt = 0; qt < 2; ++qt) {
        float l = l_part[qt];
        l += __shfl_xor(l, 16, 64);
        l += __shfl_xor(l, 32, 64);
        const float rl = 1.f / l;
        const int t = t0 + wv * 32 + qt * 16 + l16;
        short* dst = at + ((size_t)b * NT + t) * NC + hd * CH;
        #pragma unroll
        for (int ct = 0; ct < 4; ++ct) {
            int2 s;
            s.x = pk2bf_trunc(Oa[ct][qt][0] * rl, Oa[ct][qt][1] * rl);
            s.y = pk2bf_trunc(Oa[ct][qt][2] * rl, Oa[ct][qt][3] * rl);
            *(int2*)&dst[ct * 16 + quad * 4] = s;
        }
    }
}

// ---------------------------------------------------------------------------
// Proj GEMM + bias + residual: same BK=64 + XOR-swizzle treatment as qkv.
// XCD-aware remap kept. Epilogue unchanged.
// ---------------------------------------------------------------------------
__global__ __launch_bounds__(256) void proj_gemm_kernel(
    const short* __restrict__ wb, const short* __restrict__ at,
    const float* __restrict__ bias, const float* __restrict__ xres,
    float* __restrict__ out)
{
    __shared__ short As[128 * BK];
    __shared__ short Bs[128 * BK];
    const int tid = threadIdx.x;
    const int wv = tid >> 6, lane = tid & 63;
    const int l16 = lane & 15, quad = lane >> 4;
    const int xr = l16 & 7;
    const int fblk = blockIdx.y * 128 + blockIdx.x;   // x-fastest flat id
    const int jx = fblk >> 3, xcd = fblk & 7;
    const int n0 = (xcd * 16 + (jx >> 2)) * 128;
    const int m0 = (jx & 3) * 128;
    const int wm = wv & 1, wn = wv >> 1;

    floatx4 acc[4][4];
    #pragma unroll
    for (int i = 0; i < 4; ++i)
        #pragma unroll
        for (int j = 0; j < 4; ++j) acc[i][j] = (floatx4){0.f, 0.f, 0.f, 0.f};

    const short* gsrc = (wv < 2) ? wb : at;
    const int rbase = (wv & 1) * 64;
    const int tile0 = (wv < 2) ? m0 : n0;
    short* lbuf = (wv < 2) ? As : Bs;
    const int srow = lane >> 3;
    const int schk = lane & 7;

    for (int k0 = 0; k0 < 512; k0 += BK) {
        __syncthreads();
        #pragma unroll
        for (int ch = 0; ch < 8; ++ch) {
            const int row = rbase + ch * 8 + srow;
            const int cc = schk ^ (row & 7);
            gload_lds16(gsrc + (size_t)(tile0 + row) * 512 + k0 + cc * 8,
                        lbuf + (rbase + ch * 8) * BK);
        }
        __syncthreads();

        #pragma unroll
        for (int ks = 0; ks < 2; ++ks) {
            const int c = (quad | (ks << 2)) ^ xr;
            short8 af[4], bfr[4];
            #pragma unroll
            for (int i = 0; i < 4; ++i) {
                af[i]  = *(const short8*)&As[(wm * 64 + i * 16 + l16) * BK + c * 8];
                bfr[i] = *(const short8*)&Bs[(wn * 64 + i * 16 + l16) * BK + c * 8];
            }
            #pragma unroll
            for (int i = 0; i < 4; ++i)
                #pragma unroll
                for (int j = 0; j < 4; ++j)
                    acc[i][j] = __builtin_amdgcn_mfma_f32_16x16x32_bf16(
                        af[i], bfr[j], acc[i][j], 0, 0, 0);
        }
    }

    #pragma unroll
    for (int i = 0; i < 4; ++i) {
        const int o16 = m0 + wm * 64 + i * 16;
        const float4 b4 = *(const float4*)&bias[o16 + quad * 4];
        #pragma unroll
        for (int j = 0; j < 4; ++j) {
            const int tg = n0 + wn * 64 + j * 16 + l16;
            const int b = tg >> 11, t = tg & 2047;
            const size_t base = ((size_t)b * NC + o16 + quad * 4) * NT + t;
            floatx4 v = acc[i][j];
            out[base]          = v[0] + b4.x + xres[base];
            out[base + NT]     = v[1] + b4.y + xres[base + NT];
            out[base + 2 * NT] = v[2] + b4.z + xres[base + 2 * NT];
            out[base + 3 * NT] = v[3] + b4.w + xres[base + 3 * NT];
        }
    }
}

// ---------------------------------------------------------------------------
extern "C" void kernel_launch(void* const* d_in, const int* in_sizes, int n_in,
                              void* d_out, int out_size, void* d_ws, size_t ws_size,
                              hipStream_t stream)
{
    const float* x      = (const float*)d_in[0];
    const float* gn_w   = (const float*)d_in[1];
    const float* gn_b   = (const float*)d_in[2];
    const float* qkv_w  = (const float*)d_in[3];
    const float* qkv_b  = (const float*)d_in[4];
    const float* proj_w = (const float*)d_in[5];
    const float* proj_b = (const float*)d_in[6];
    float* out = (float*)d_out;

    short* ht  = (short*)d_ws;            // [8*2048][512]
    short* q_t = ht  + 8388608;           // [64][2048][64]
    short* k_t = q_t + 8388608;
    short* vv  = k_t + 8388608;           // [64][64][2048]
    short* at  = vv  + 8388608;           // [8*2048][512]
    short* qwb = at  + 8388608;           // [1536][512]
    short* pwb = qwb + 786432;            // [512][512]

    castw_kernel<<<1024, 256, 0, stream>>>(qkv_w, proj_w, qwb, pwb);
    gn_fused_kernel<<<NB * NG, 256, 0, stream>>>(x, gn_w, gn_b, ht);
    qkv_gemm_kernel<<<dim3(128, 12), 256, 0, stream>>>(qwb, ht, qkv_b, q_t, k_t, vv);
    attn_kernel<<<dim3(8, 64), 512, 0, stream>>>(q_t, k_t, vv, at);
    proj_gemm_kernel<<<dim3(128, 4), 256, 0, stream>>>(pwb, at, proj_b, x, out);
}